// Round 10
// baseline (244.052 us; speedup 1.0000x reference)
//
#include <hip/hip_runtime.h>
#include <stdint.h>

// GATConv: N=100000 nodes, E=1600000 edges, IN=128, HEADS=4, OUT=32 (HO=128)
// fp32 tensors; edge_index int32.
//
// R15: gemm_h and bucketA_k are data-independent (x/W vs ei) but ran
// sequentially, each paying its own latency tail (~70 us combined, both
// memory-phase-heavy). Fused into one grid-partitioned kernel fusedGA_k
// (blockIdx<3125 -> gemm body, else bucketA body; LDS aliased 16KB/4.7KB;
// hipEvent* is banned so multi-stream fork is not an option). gcur zeroing
// folded into prepW_k block 0 (memset dispatch removed). gather_k kept at the
// thrice-measured R9 structure (65.5/66.4/66.5 us); bucketB unchanged.

#define NN 100000
#define EE 1600000
#define INCH 128
#define HO 128           // HEADS*OUT
#define HEADS 4
#define OUTC 32

#define BSH 8                             // 256 nodes per bucket
#define NBUCK ((NN + 255) >> BSH)         // 391
#define CAPBK 5120                        // fixed bucket capacity (16 sigma)
#define CHA 4096                          // edges per bucketA block
#define ABLK ((EE + CHA - 1) / CHA)       // 391
#define GEMMB (NN / 32)                   // 3125 gemm blocks

typedef unsigned short ushort_t;
typedef unsigned int uint_t;
typedef __attribute__((ext_vector_type(8))) short bf16x8;   // 8 bf16 (4 VGPRs)
typedef __attribute__((ext_vector_type(4))) float f32x4;    // MFMA C/D

__device__ __forceinline__ float bfl(uint_t u) { return __uint_as_float(u << 16); }
__device__ __forceinline__ float bfh(uint_t u) { return __uint_as_float(u & 0xffff0000u); }
__device__ __forceinline__ uint_t f2bf(float f) {
    uint_t u = __float_as_uint(f);
    u = (u + 0x7fffu + ((u >> 16) & 1u)) >> 16;   // round-to-nearest-even
    return u;
}
__device__ __forceinline__ float att_w(float sc) {
    return __expf(-(sc > 0.f ? sc : 0.2f * sc));
}

// ---------------- prep: W -> transposed bf16 hi/lo images; block 0 zeros gcur
__global__ __launch_bounds__(256) void prepW_k(const float* __restrict__ W,
                                               ushort_t* __restrict__ gWtHi,
                                               ushort_t* __restrict__ gWtLo,
                                               int* __restrict__ gcur) {
    if (blockIdx.x == 0) {
        for (int i = threadIdx.x; i < NBUCK; i += 256) gcur[i] = 0;
    }
    const int gidx = blockIdx.x * 256 + threadIdx.x;   // 16384 = 128*128
    const int col = gidx & 127;
    const int k = gidx >> 7;
    const float v = W[k * 128 + col];
    const uint_t h = f2bf(v);
    const uint_t lo = f2bf(v - bfl(h));
    gWtHi[col * 128 + k] = (ushort_t)h;
    gWtLo[col * 128 + k] = (ushort_t)lo;
}

// ---------------- fused: gemm (blocks 0..3124) + bucketA (blocks 3125..3515)
__global__ __launch_bounds__(256) void fusedGA_k(const float* __restrict__ x,
                                                 const ushort_t* __restrict__ gWtHi,
                                                 const ushort_t* __restrict__ gWtLo,
                                                 const float* __restrict__ att,
                                                 ushort_t* __restrict__ hb,
                                                 float* __restrict__ s_src,
                                                 float* __restrict__ s_tgt,
                                                 const int* __restrict__ ei,
                                                 int* __restrict__ gcur,
                                                 uint_t* __restrict__ grec) {
    __shared__ __align__(16) char smem[16384];
    const int tid = threadIdx.x;

    if (blockIdx.x >= GEMMB) {
        // ---------- bucketA: direct bucketed scatter into fixed-cap regions
        int* hist  = (int*)smem;
        int* gbase = hist + NBUCK;
        int* lcur  = gbase + NBUCK;
        const int e0 = (blockIdx.x - GEMMB) * CHA;
        const int cnt = min(CHA, EE - e0);

        for (int b = tid; b < NBUCK; b += 256) hist[b] = 0;
        __syncthreads();
        for (int i = tid; i < cnt; i += 256)
            atomicAdd(&hist[ei[EE + e0 + i] >> BSH], 1);
        __syncthreads();
        for (int b = tid; b < NBUCK; b += 256) {
            const int h = hist[b];
            gbase[b] = b * CAPBK + (h ? atomicAdd(&gcur[b], h) : 0);
            lcur[b] = 0;
        }
        __syncthreads();
        for (int i = tid; i < cnt; i += 256) {
            const int src = ei[e0 + i];
            const int tgt = ei[EE + e0 + i];
            const int b = tgt >> BSH;
            const int p = atomicAdd(&lcur[b], 1);
            grec[gbase[b] + p] = (uint_t)src | ((uint_t)(tgt & 255) << 17);  // src<2^17
        }
        return;
    }

    // ---------- gemm via bf16x3 MFMA, W in registers, x in 16KB LDS
    ushort_t* xHi = (ushort_t*)smem;                     // 8 KB (32x128 bf16)
    ushort_t* xLo = (ushort_t*)(smem + 8192);            // 8 KB
    const int row0 = blockIdx.x * 32;

    const int lane = tid & 63;
    const int w = tid >> 6;            // wave id = head id
    const int l15 = lane & 15;
    const int g = lane >> 4;           // k-group (A/B) and row-group (C/D)
    const int swz = (l15 & 7) << 4;

    // B fragments -> registers (16 x 16B loads from L2-broadcast images)
    bf16x8 bh[2][4], bl[2][4];
    {
        const ushort_t* pH = gWtHi + (size_t)(w * 32 + l15) * 128 + g * 8;
        const ushort_t* pL = gWtLo + (size_t)(w * 32 + l15) * 128 + g * 8;
#pragma unroll
        for (int ntl = 0; ntl < 2; ++ntl)
#pragma unroll
            for (int ks = 0; ks < 4; ++ks) {
                bh[ntl][ks] = *(const bf16x8*)(pH + ntl * 16 * 128 + ks * 32);
                bl[ntl][ks] = *(const bf16x8*)(pL + ntl * 16 * 128 + ks * 32);
            }
    }

    // stage x tile 32x128 fp32 -> bf16 hi/lo, row-swizzled
    {
        const float4* x4 = (const float4*)(x + (size_t)row0 * INCH);
#pragma unroll
        for (int j = 0; j < 4; ++j) {
            const int i = tid + 256 * j;          // float4 id (0..1023)
            const int row = i >> 5;               // 32 float4 per row
            const int k4 = i & 31;                // k = k4*4
            const float4 v = x4[i];
            const uint_t h0 = f2bf(v.x), h1 = f2bf(v.y), h2 = f2bf(v.z), h3 = f2bf(v.w);
            const uint_t l0 = f2bf(v.x - bfl(h0));
            const uint_t l1 = f2bf(v.y - bfl(h1));
            const uint_t l2 = f2bf(v.z - bfl(h2));
            const uint_t l3 = f2bf(v.w - bfl(h3));
            const int byteOff = (row * 256 + k4 * 8) ^ ((row & 7) << 4);
            *(uint2*)((char*)xHi + byteOff) = make_uint2(h0 | (h1 << 16), h2 | (h3 << 16));
            *(uint2*)((char*)xLo + byteOff) = make_uint2(l0 | (l1 << 16), l2 | (l3 << 16));
        }
    }
    __syncthreads();

    f32x4 acc[2][2] = {};              // [mtile][ntile-local]
#pragma unroll
    for (int ks = 0; ks < 4; ++ks) {   // K = 4 x 32
        const int kb = ks * 64 + g * 16;                   // byte offset along k
        const bf16x8 a0h = *(const bf16x8*)((char*)xHi + ((l15 * 256 + kb) ^ swz));
        const bf16x8 a1h = *(const bf16x8*)((char*)xHi + (((16 + l15) * 256 + kb) ^ swz));
        const bf16x8 a0l = *(const bf16x8*)((char*)xLo + ((l15 * 256 + kb) ^ swz));
        const bf16x8 a1l = *(const bf16x8*)((char*)xLo + (((16 + l15) * 256 + kb) ^ swz));
        acc[0][0] = __builtin_amdgcn_mfma_f32_16x16x32_bf16(a0h, bh[0][ks], acc[0][0], 0, 0, 0);
        acc[0][1] = __builtin_amdgcn_mfma_f32_16x16x32_bf16(a0h, bh[1][ks], acc[0][1], 0, 0, 0);
        acc[1][0] = __builtin_amdgcn_mfma_f32_16x16x32_bf16(a1h, bh[0][ks], acc[1][0], 0, 0, 0);
        acc[1][1] = __builtin_amdgcn_mfma_f32_16x16x32_bf16(a1h, bh[1][ks], acc[1][1], 0, 0, 0);
        acc[0][0] = __builtin_amdgcn_mfma_f32_16x16x32_bf16(a0h, bl[0][ks], acc[0][0], 0, 0, 0);
        acc[0][1] = __builtin_amdgcn_mfma_f32_16x16x32_bf16(a0h, bl[1][ks], acc[0][1], 0, 0, 0);
        acc[1][0] = __builtin_amdgcn_mfma_f32_16x16x32_bf16(a1h, bl[0][ks], acc[1][0], 0, 0, 0);
        acc[1][1] = __builtin_amdgcn_mfma_f32_16x16x32_bf16(a1h, bl[1][ks], acc[1][1], 0, 0, 0);
        acc[0][0] = __builtin_amdgcn_mfma_f32_16x16x32_bf16(a0l, bh[0][ks], acc[0][0], 0, 0, 0);
        acc[0][1] = __builtin_amdgcn_mfma_f32_16x16x32_bf16(a0l, bh[1][ks], acc[0][1], 0, 0, 0);
        acc[1][0] = __builtin_amdgcn_mfma_f32_16x16x32_bf16(a1l, bh[0][ks], acc[1][0], 0, 0, 0);
        acc[1][1] = __builtin_amdgcn_mfma_f32_16x16x32_bf16(a1l, bh[1][ks], acc[1][1], 0, 0, 0);
    }

    // hb writeout: D layout col = l15, row = g*4 + reg
#pragma unroll
    for (int mt = 0; mt < 2; ++mt)
#pragma unroll
        for (int ntl = 0; ntl < 2; ++ntl) {
            const int col = w * 32 + ntl * 16 + l15;
#pragma unroll
            for (int r = 0; r < 4; ++r) {
                const int row = row0 + mt * 16 + g * 4 + r;
                hb[(size_t)row * HO + col] = (ushort_t)f2bf(acc[mt][ntl][r]);
            }
        }

    // score epilogue: wave w owns head w; reduce over the 16 col-lanes
    const float cs0 = att[w * 64 + l15];
    const float cs1 = att[w * 64 + 16 + l15];
    const float ct0 = att[w * 64 + 32 + l15];
    const float ct1 = att[w * 64 + 48 + l15];
#pragma unroll
    for (int mt = 0; mt < 2; ++mt)
#pragma unroll
        for (int r = 0; r < 4; ++r) {
            float ps = acc[mt][0][r] * cs0 + acc[mt][1][r] * cs1;
            float pt = acc[mt][0][r] * ct0 + acc[mt][1][r] * ct1;
#pragma unroll
            for (int d = 1; d < 16; d <<= 1) {
                ps += __shfl_xor(ps, d, 64);
                pt += __shfl_xor(pt, d, 64);
            }
            if (l15 == 0) {
                const int row = row0 + mt * 16 + g * 4 + r;
                s_src[row * 4 + w] = ps;
                s_tgt[row * 4 + w] = pt;
            }
        }
}

// ---------------- bucket pass B: offs2 + counting sort + wgt precompute
__global__ __launch_bounds__(1024) void bucketB_k(const int* __restrict__ bucketCnt,
                                                  const uint_t* __restrict__ grec,
                                                  const float* __restrict__ s_src,
                                                  const float* __restrict__ s_tgt,
                                                  int2* __restrict__ offs2,
                                                  int* __restrict__ sorted_src,
                                                  float4* __restrict__ wgt) {
    __shared__ int cur[256];
    __shared__ int scn[256];
    __shared__ uint_t sbuf[CAPBK];      // 20 KB
    const int tid = threadIdx.x;
    const int b = blockIdx.x;
    const int n0 = b << BSH;
    const int nn = min(256, NN - n0);
    const int R0 = b * CAPBK;
    const int cnt = min(bucketCnt[b], CAPBK);

    if (tid < 256) cur[tid] = 0;
    __syncthreads();
    // phase 1: stage records into fixed registers + per-node counts in LDS
    uint_t r0v = 0xFFFFFFFFu, r1v = 0xFFFFFFFFu, r2v = 0xFFFFFFFFu,
           r3v = 0xFFFFFFFFu, r4v = 0xFFFFFFFFu;
    {
        int i = tid;
        if (i < cnt) { r0v = grec[R0 + i]; atomicAdd(&cur[r0v >> 17], 1); } i += 1024;
        if (i < cnt) { r1v = grec[R0 + i]; atomicAdd(&cur[r1v >> 17], 1); } i += 1024;
        if (i < cnt) { r2v = grec[R0 + i]; atomicAdd(&cur[r2v >> 17], 1); } i += 1024;
        if (i < cnt) { r3v = grec[R0 + i]; atomicAdd(&cur[r3v >> 17], 1); } i += 1024;
        if (i < cnt) { r4v = grec[R0 + i]; atomicAdd(&cur[r4v >> 17], 1); }
    }
    __syncthreads();
    // phase 2: 256-entry exclusive scan -> node-local offsets; write offs2
    int v = 0;
    if (tid < 256) { v = cur[tid]; scn[tid] = v; }
    __syncthreads();
#pragma unroll
    for (int off = 1; off < 256; off <<= 1) {
        int u = (tid < 256 && tid >= off) ? scn[tid - off] : 0;
        __syncthreads();
        if (tid < 256) scn[tid] += u;
        __syncthreads();
    }
    if (tid < 256) {
        const int ex = scn[tid] - v;
        cur[tid] = ex;
        if (tid < nn) offs2[n0 + tid] = make_int2(R0 + ex, R0 + ex + v);
    }
    __syncthreads();
    // phase 3: scatter staged records into LDS (counting sort)
    if (r0v != 0xFFFFFFFFu) sbuf[atomicAdd(&cur[r0v >> 17], 1)] = r0v;
    if (r1v != 0xFFFFFFFFu) sbuf[atomicAdd(&cur[r1v >> 17], 1)] = r1v;
    if (r2v != 0xFFFFFFFFu) sbuf[atomicAdd(&cur[r2v >> 17], 1)] = r2v;
    if (r3v != 0xFFFFFFFFu) sbuf[atomicAdd(&cur[r3v >> 17], 1)] = r3v;
    if (r4v != 0xFFFFFFFFu) sbuf[atomicAdd(&cur[r4v >> 17], 1)] = r4v;
    __syncthreads();
    // phase 4: coalesced writeout + fused per-(edge,head) weight precompute
    for (int i = tid; i < cnt; i += 1024) {
        const uint_t r = sbuf[i];
        const int src = (int)(r & 0x1FFFF);
        const int tl = (int)(r >> 17);
        sorted_src[R0 + i] = src;
        const float4 ss = *(const float4*)(s_src + src * 4);
        const float4 st = *(const float4*)(s_tgt + (n0 + tl) * 4);
        float4 wv;
        wv.x = att_w(ss.x + st.x);
        wv.y = att_w(ss.y + st.y);
        wv.z = att_w(ss.z + st.z);
        wv.w = att_w(ss.w + st.w);
        wgt[R0 + i] = wv;
    }
}

// ---------------- gather: R9 structure — readlane bcast + 8-deep load burst
template <bool PRED>
__device__ __forceinline__ void gat8(const float* __restrict__ wgt,
                                     const ushort_t* __restrict__ hb,
                                     int srcv, int p0, int p1, int base, int e, int m,
                                     int hd, int c0, float& ax, float& ay, float& wsum) {
    int s[8]; float w[8]; uint_t v[8];
#pragma unroll
    for (int j = 0; j < 8; ++j)
        s[j] = __builtin_amdgcn_readlane(srcv, (e + j) & 63);   // uniform, no DS trip
#pragma unroll
    for (int j = 0; j < 8; ++j) {
        int idx = p0 + base + e + j;
        if (PRED) idx = min(idx, p1 - 1);                       // keep in-range
        const float wl = wgt[(uint_t)idx * 4u + hd];
        w[j] = (PRED && (e + j >= m)) ? 0.f : wl;               // mask tail edges
    }
#pragma unroll
    for (int j = 0; j < 8; ++j)
        v[j] = *(const uint_t*)(hb + (uint_t)(s[j] * HO + c0));
#pragma unroll
    for (int j = 0; j < 8; ++j) {
        ax = fmaf(w[j], bfl(v[j]), ax);
        ay = fmaf(w[j], bfh(v[j]), ay);
    }
    wsum += ((w[0] + w[1]) + (w[2] + w[3])) + ((w[4] + w[5]) + (w[6] + w[7]));
}

__global__ __launch_bounds__(256) void gather_k(const int2* __restrict__ offs2,
                                                const int* __restrict__ sorted_src,
                                                const float* __restrict__ wgt,
                                                const ushort_t* __restrict__ hb,
                                                const float* __restrict__ bias,
                                                float* __restrict__ out) {
    const int n = blockIdx.x * 4 + (threadIdx.x >> 6);
    const int l = threadIdx.x & 63;
    const int c0 = l * 2;              // two channels per lane (same head)
    const int hd = l >> 4;
    const int2 pr = offs2[n];
    const int p0 = pr.x, p1 = pr.y;
    const int deg = p1 - p0;
    float ax = 0.f, ay = 0.f, wsum = 0.f;
    for (int base = 0; base < deg; base += 64) {
        const int m = min(deg - base, 64);
        // one lane-parallel load fetches up to 64 src indices for this node
        const int srcv = sorted_src[p0 + base + ((l < m) ? l : 0)];
        int e = 0;
        for (; e + 8 <= m; e += 8)
            gat8<false>(wgt, hb, srcv, p0, p1, base, e, m, hd, c0, ax, ay, wsum);
        if (e < m)
            gat8<true>(wgt, hb, srcv, p0, p1, base, e, m, hd, c0, ax, ay, wsum);
    }
    const float inv = 1.f / fmaxf(wsum, 1e-10f);
    float2 o;
    o.x = ax * inv + bias[c0];
    o.y = ay * inv + bias[c0 + 1];
    *(float2*)(out + (size_t)n * HO + c0) = o;
}

extern "C" void kernel_launch(void* const* d_in, const int* in_sizes, int n_in,
                              void* d_out, int out_size, void* d_ws, size_t ws_size,
                              hipStream_t stream) {
    const float* x    = (const float*)d_in[0];
    const int*   ei   = (const int*)d_in[1];
    const float* W    = (const float*)d_in[2];
    const float* att  = (const float*)d_in[3];
    const float* bias = (const float*)d_in[4];
    float* out = (float*)d_out;

    char* ws = (char*)d_ws;
    const size_t HB_B  = (size_t)NN * HO * 2;              // 25.6 MB (bf16 h)
    const size_t SS_B  = (size_t)NBUCK * CAPBK * 4;        // 8.0 MB
    const size_t GR_B  = (size_t)NBUCK * CAPBK * 4;        // 8.0 MB
    const size_t WG_B  = (size_t)NBUCK * CAPBK * 16;       // 32.0 MB
    const size_t S_B   = (size_t)NN * HEADS * 4;           // 1.6 MB
    const size_t OF_B  = ((size_t)NN * 8 + 15) & ~15ull;   // 800 KB (int2)
    const size_t GC_B  = ((size_t)NBUCK * 4 + 15) & ~15ull;
    const size_t WT_B  = 32768;                            // 32 KB per W image

    size_t o = 0;
    ushort_t* hb         = (ushort_t*)(ws + o); o += HB_B;
    int*      sorted_src = (int*)(ws + o); o += SS_B;
    uint_t*   grec       = (uint_t*)(ws + o); o += GR_B;
    float4*   wgt        = (float4*)(ws + o); o += WG_B;
    float*    ssrc       = (float*)(ws + o); o += S_B;
    float*    stgt       = (float*)(ws + o); o += S_B;
    int2*     offs2      = (int2*)(ws + o); o += OF_B;
    int*      gcur       = (int*)(ws + o); o += GC_B;
    ushort_t* gWtHi      = (ushort_t*)(ws + o); o += WT_B;
    ushort_t* gWtLo      = (ushort_t*)(ws + o); o += WT_B;

    prepW_k<<<64, 256, 0, stream>>>(W, gWtHi, gWtLo, gcur);               // + gcur zero
    fusedGA_k<<<GEMMB + ABLK, 256, 0, stream>>>(x, gWtHi, gWtLo, att,
                                                hb, ssrc, stgt,
                                                ei, gcur, grec);          // 3516 blocks
    bucketB_k<<<NBUCK, 1024, 0, stream>>>(gcur, grec, ssrc, stgt,
                                          offs2, sorted_src, wgt);        // 391 blocks
    gather_k<<<NN / 4, 256, 0, stream>>>(offs2, sorted_src, (const float*)wgt,
                                         hb, bias, out);                  // 25000 blocks
}

// Round 11
// 241.908 us; speedup vs baseline: 1.0089x; 1.0089x over previous
//
#include <hip/hip_runtime.h>
#include <stdint.h>

// GATConv: N=100000 nodes, E=1600000 edges, IN=128, HEADS=4, OUT=32 (HO=128)
// fp32 tensors; edge_index int32.
//
// R16: pipeline re-plumbing. R15's fusion put the 391 bucketA blocks LAST ->
// zero overlap (fused dur = sum, 80us). And bucketB measured ~70-75us hidden
// under the top-5 cutoff. Now: (1) bucketB split into sortB (counting sort,
// needs only grec) + wgt_k (streaming weight pass, needs gemm scores);
// (2) kernel1 = bucketA(first) || prepW, kernel2 = sortB(first) || gemm —
// small grid FIRST so it resides on CUs while the big grid streams past;
// (3) gather keeps the thrice-measured R9 structure, reads packed records
// (& 0x1FFFF after readlane, SALU-free). Chain: memset -> PA -> GS -> wgt ->
// gather.

#define NN 100000
#define EE 1600000
#define INCH 128
#define HO 128           // HEADS*OUT
#define HEADS 4
#define OUTC 32

#define BSH 8                             // 256 nodes per bucket
#define NBUCK ((NN + 255) >> BSH)         // 391
#define CAPBK 5120                        // fixed bucket capacity (16 sigma)
#define CHA 4096                          // edges per bucketA block
#define ABLK ((EE + CHA - 1) / CHA)       // 391
#define GEMMB (NN / 32)                   // 3125 gemm blocks
#define NSLOT (NBUCK * CAPBK)             // 2001920 slots

typedef unsigned short ushort_t;
typedef unsigned int uint_t;
typedef __attribute__((ext_vector_type(8))) short bf16x8;   // 8 bf16 (4 VGPRs)
typedef __attribute__((ext_vector_type(4))) float f32x4;    // MFMA C/D

__device__ __forceinline__ float bfl(uint_t u) { return __uint_as_float(u << 16); }
__device__ __forceinline__ float bfh(uint_t u) { return __uint_as_float(u & 0xffff0000u); }
__device__ __forceinline__ uint_t f2bf(float f) {
    uint_t u = __float_as_uint(f);
    u = (u + 0x7fffu + ((u >> 16) & 1u)) >> 16;   // round-to-nearest-even
    return u;
}
__device__ __forceinline__ float att_w(float sc) {
    return __expf(-(sc > 0.f ? sc : 0.2f * sc));
}

// ---------------- kernel 1: bucketA (blocks 0..390, FIRST) || prepW (32 blocks)
__global__ __launch_bounds__(512) void fusedPA_k(const int* __restrict__ ei,
                                                 int* __restrict__ gcur,
                                                 uint_t* __restrict__ grec,
                                                 const float* __restrict__ W,
                                                 ushort_t* __restrict__ gWtHi,
                                                 ushort_t* __restrict__ gWtLo) {
    __shared__ int hist[NBUCK];
    __shared__ int gbase[NBUCK];
    __shared__ int lcur[NBUCK];
    const int tid = threadIdx.x;

    if (blockIdx.x >= ABLK) {
        // ---- prepW: W -> transposed bf16 hi/lo images
        const int gidx = (blockIdx.x - ABLK) * 512 + tid;  // 16384 = 128*128
        const int col = gidx & 127;
        const int k = gidx >> 7;
        const float v = W[k * 128 + col];
        const uint_t h = f2bf(v);
        const uint_t lo = f2bf(v - bfl(h));
        gWtHi[col * 128 + k] = (ushort_t)h;
        gWtLo[col * 128 + k] = (ushort_t)lo;
        return;
    }
    // ---- bucketA: direct bucketed scatter into fixed-cap regions
    const int e0 = blockIdx.x * CHA;
    const int cnt = min(CHA, EE - e0);

    for (int b = tid; b < NBUCK; b += 512) hist[b] = 0;
    __syncthreads();
    for (int i = tid; i < cnt; i += 512)
        atomicAdd(&hist[ei[EE + e0 + i] >> BSH], 1);
    __syncthreads();
    for (int b = tid; b < NBUCK; b += 512) {
        const int h = hist[b];
        gbase[b] = b * CAPBK + (h ? atomicAdd(&gcur[b], h) : 0);
        lcur[b] = 0;
    }
    __syncthreads();
    for (int i = tid; i < cnt; i += 512) {
        const int src = ei[e0 + i];
        const int tgt = ei[EE + e0 + i];
        const int b = tgt >> BSH;
        const int p = atomicAdd(&lcur[b], 1);
        grec[gbase[b] + p] = (uint_t)src | ((uint_t)(tgt & 255) << 17);   // src<2^17
    }
}

// ---------------- kernel 2: sortB (blocks 0..390, FIRST) || gemm (3125 blocks)
__global__ __launch_bounds__(256) void fusedGS_k(const uint_t* __restrict__ grec,
                                                 const int* __restrict__ gcur,
                                                 int2* __restrict__ offs2,
                                                 uint_t* __restrict__ srec,
                                                 const float* __restrict__ x,
                                                 const ushort_t* __restrict__ gWtHi,
                                                 const ushort_t* __restrict__ gWtLo,
                                                 const float* __restrict__ att,
                                                 ushort_t* __restrict__ hb,
                                                 float* __restrict__ s_src,
                                                 float* __restrict__ s_tgt) {
    __shared__ __align__(16) char smem[22528];   // sortB: 20K sbuf + 2x1K | gemm: 16K
    const int tid = threadIdx.x;

    if (blockIdx.x < NBUCK) {
        // ---- sortB: per-node offs2 + counting sort -> packed srec
        uint_t* sbuf = (uint_t*)smem;                    // 20 KB
        int* cur = (int*)(smem + 20480);                 // 1 KB
        int* scn = (int*)(smem + 21504);                 // 1 KB
        const int b = blockIdx.x;
        const int n0 = b << BSH;
        const int nn = min(256, NN - n0);
        const int R0 = b * CAPBK;
        const int cnt = min(gcur[b], CAPBK);

        cur[tid] = 0;
        __syncthreads();
        for (int i = tid; i < cnt; i += 256)
            atomicAdd(&cur[grec[R0 + i] >> 17], 1);
        __syncthreads();
        const int v = cur[tid];
        scn[tid] = v;
        __syncthreads();
#pragma unroll
        for (int off = 1; off < 256; off <<= 1) {
            int u = (tid >= off) ? scn[tid - off] : 0;
            __syncthreads();
            scn[tid] += u;
            __syncthreads();
        }
        const int ex = scn[tid] - v;
        cur[tid] = ex;
        if (tid < nn) offs2[n0 + tid] = make_int2(R0 + ex, R0 + ex + v);
        __syncthreads();
        for (int i = tid; i < cnt; i += 256) {
            const uint_t r = grec[R0 + i];               // L2-hot second read
            const int p = atomicAdd(&cur[r >> 17], 1);
            sbuf[p] = r;
        }
        __syncthreads();
        for (int i = tid; i < cnt; i += 256)
            srec[R0 + i] = sbuf[i];                      // coalesced writeout
        return;
    }

    // ---- gemm via bf16x3 MFMA, W in registers, x in 16KB LDS
    ushort_t* xHi = (ushort_t*)smem;                     // 8 KB (32x128 bf16)
    ushort_t* xLo = (ushort_t*)(smem + 8192);            // 8 KB
    const int row0 = (blockIdx.x - NBUCK) * 32;

    const int lane = tid & 63;
    const int w = tid >> 6;            // wave id = head id
    const int l15 = lane & 15;
    const int g = lane >> 4;           // k-group (A/B) and row-group (C/D)
    const int swz = (l15 & 7) << 4;

    // B fragments -> registers (16 x 16B loads from L2-broadcast images)
    bf16x8 bh[2][4], bl[2][4];
    {
        const ushort_t* pH = gWtHi + (size_t)(w * 32 + l15) * 128 + g * 8;
        const ushort_t* pL = gWtLo + (size_t)(w * 32 + l15) * 128 + g * 8;
#pragma unroll
        for (int ntl = 0; ntl < 2; ++ntl)
#pragma unroll
            for (int ks = 0; ks < 4; ++ks) {
                bh[ntl][ks] = *(const bf16x8*)(pH + ntl * 16 * 128 + ks * 32);
                bl[ntl][ks] = *(const bf16x8*)(pL + ntl * 16 * 128 + ks * 32);
            }
    }

    // stage x tile 32x128 fp32 -> bf16 hi/lo, row-swizzled
    {
        const float4* x4 = (const float4*)(x + (size_t)row0 * INCH);
#pragma unroll
        for (int j = 0; j < 4; ++j) {
            const int i = tid + 256 * j;          // float4 id (0..1023)
            const int row = i >> 5;               // 32 float4 per row
            const int k4 = i & 31;                // k = k4*4
            const float4 v = x4[i];
            const uint_t h0 = f2bf(v.x), h1 = f2bf(v.y), h2 = f2bf(v.z), h3 = f2bf(v.w);
            const uint_t l0 = f2bf(v.x - bfl(h0));
            const uint_t l1 = f2bf(v.y - bfl(h1));
            const uint_t l2 = f2bf(v.z - bfl(h2));
            const uint_t l3 = f2bf(v.w - bfl(h3));
            const int byteOff = (row * 256 + k4 * 8) ^ ((row & 7) << 4);
            *(uint2*)((char*)xHi + byteOff) = make_uint2(h0 | (h1 << 16), h2 | (h3 << 16));
            *(uint2*)((char*)xLo + byteOff) = make_uint2(l0 | (l1 << 16), l2 | (l3 << 16));
        }
    }
    __syncthreads();

    f32x4 acc[2][2] = {};              // [mtile][ntile-local]
#pragma unroll
    for (int ks = 0; ks < 4; ++ks) {   // K = 4 x 32
        const int kb = ks * 64 + g * 16;                   // byte offset along k
        const bf16x8 a0h = *(const bf16x8*)((char*)xHi + ((l15 * 256 + kb) ^ swz));
        const bf16x8 a1h = *(const bf16x8*)((char*)xHi + (((16 + l15) * 256 + kb) ^ swz));
        const bf16x8 a0l = *(const bf16x8*)((char*)xLo + ((l15 * 256 + kb) ^ swz));
        const bf16x8 a1l = *(const bf16x8*)((char*)xLo + (((16 + l15) * 256 + kb) ^ swz));
        acc[0][0] = __builtin_amdgcn_mfma_f32_16x16x32_bf16(a0h, bh[0][ks], acc[0][0], 0, 0, 0);
        acc[0][1] = __builtin_amdgcn_mfma_f32_16x16x32_bf16(a0h, bh[1][ks], acc[0][1], 0, 0, 0);
        acc[1][0] = __builtin_amdgcn_mfma_f32_16x16x32_bf16(a1h, bh[0][ks], acc[1][0], 0, 0, 0);
        acc[1][1] = __builtin_amdgcn_mfma_f32_16x16x32_bf16(a1h, bh[1][ks], acc[1][1], 0, 0, 0);
        acc[0][0] = __builtin_amdgcn_mfma_f32_16x16x32_bf16(a0h, bl[0][ks], acc[0][0], 0, 0, 0);
        acc[0][1] = __builtin_amdgcn_mfma_f32_16x16x32_bf16(a0h, bl[1][ks], acc[0][1], 0, 0, 0);
        acc[1][0] = __builtin_amdgcn_mfma_f32_16x16x32_bf16(a1h, bl[0][ks], acc[1][0], 0, 0, 0);
        acc[1][1] = __builtin_amdgcn_mfma_f32_16x16x32_bf16(a1h, bl[1][ks], acc[1][1], 0, 0, 0);
        acc[0][0] = __builtin_amdgcn_mfma_f32_16x16x32_bf16(a0l, bh[0][ks], acc[0][0], 0, 0, 0);
        acc[0][1] = __builtin_amdgcn_mfma_f32_16x16x32_bf16(a0l, bh[1][ks], acc[0][1], 0, 0, 0);
        acc[1][0] = __builtin_amdgcn_mfma_f32_16x16x32_bf16(a1l, bh[0][ks], acc[1][0], 0, 0, 0);
        acc[1][1] = __builtin_amdgcn_mfma_f32_16x16x32_bf16(a1l, bh[1][ks], acc[1][1], 0, 0, 0);
    }

    // hb writeout: D layout col = l15, row = g*4 + reg
#pragma unroll
    for (int mt = 0; mt < 2; ++mt)
#pragma unroll
        for (int ntl = 0; ntl < 2; ++ntl) {
            const int col = w * 32 + ntl * 16 + l15;
#pragma unroll
            for (int r = 0; r < 4; ++r) {
                const int row = row0 + mt * 16 + g * 4 + r;
                hb[(size_t)row * HO + col] = (ushort_t)f2bf(acc[mt][ntl][r]);
            }
        }

    // score epilogue: wave w owns head w; reduce over the 16 col-lanes
    const float cs0 = att[w * 64 + l15];
    const float cs1 = att[w * 64 + 16 + l15];
    const float ct0 = att[w * 64 + 32 + l15];
    const float ct1 = att[w * 64 + 48 + l15];
#pragma unroll
    for (int mt = 0; mt < 2; ++mt)
#pragma unroll
        for (int r = 0; r < 4; ++r) {
            float ps = acc[mt][0][r] * cs0 + acc[mt][1][r] * cs1;
            float pt = acc[mt][0][r] * ct0 + acc[mt][1][r] * ct1;
#pragma unroll
            for (int d = 1; d < 16; d <<= 1) {
                ps += __shfl_xor(ps, d, 64);
                pt += __shfl_xor(pt, d, 64);
            }
            if (l15 == 0) {
                const int row = row0 + mt * 16 + g * 4 + r;
                s_src[row * 4 + w] = ps;
                s_tgt[row * 4 + w] = pt;
            }
        }
}

// ---------------- kernel 3: streaming per-slot weight pass
__global__ __launch_bounds__(256) void wgt_k(const uint_t* __restrict__ srec,
                                             const int* __restrict__ gcur,
                                             const float* __restrict__ s_src,
                                             const float* __restrict__ s_tgt,
                                             float4* __restrict__ wgt) {
    const int base = blockIdx.x * 2048 + threadIdx.x;
#pragma unroll
    for (int j = 0; j < 8; ++j) {
        const int slot = base + j * 256;
        if (slot >= NSLOT) return;
        const int b = (uint_t)slot / CAPBK;       // magic-mul division
        const int i = slot - b * CAPBK;
        if (i < gcur[b]) {
            const uint_t r = srec[slot];
            const int src = (int)(r & 0x1FFFF);
            const int tgt = (b << BSH) + (int)(r >> 17);
            const float4 ss = *(const float4*)(s_src + src * 4);
            const float4 st = *(const float4*)(s_tgt + tgt * 4);
            float4 wv;
            wv.x = att_w(ss.x + st.x);
            wv.y = att_w(ss.y + st.y);
            wv.z = att_w(ss.z + st.z);
            wv.w = att_w(ss.w + st.w);
            wgt[slot] = wv;
        }
    }
}

// ---------------- gather: R9 structure — readlane bcast + 8-deep load burst
template <bool PRED>
__device__ __forceinline__ void gat8(const float* __restrict__ wgt,
                                     const ushort_t* __restrict__ hb,
                                     uint_t srcv, int p0, int p1, int base, int e, int m,
                                     int hd, int c0, float& ax, float& ay, float& wsum) {
    uint_t s[8]; float w[8]; uint_t v[8];
#pragma unroll
    for (int j = 0; j < 8; ++j)
        s[j] = __builtin_amdgcn_readlane(srcv, (e + j) & 63) & 0x1FFFFu;  // unpack src
#pragma unroll
    for (int j = 0; j < 8; ++j) {
        int idx = p0 + base + e + j;
        if (PRED) idx = min(idx, p1 - 1);                       // keep in-range
        const float wl = wgt[(uint_t)idx * 4u + hd];
        w[j] = (PRED && (e + j >= m)) ? 0.f : wl;               // mask tail edges
    }
#pragma unroll
    for (int j = 0; j < 8; ++j)
        v[j] = *(const uint_t*)(hb + (uint_t)(s[j] * HO + c0));
#pragma unroll
    for (int j = 0; j < 8; ++j) {
        ax = fmaf(w[j], bfl(v[j]), ax);
        ay = fmaf(w[j], bfh(v[j]), ay);
    }
    wsum += ((w[0] + w[1]) + (w[2] + w[3])) + ((w[4] + w[5]) + (w[6] + w[7]));
}

__global__ __launch_bounds__(256) void gather_k(const int2* __restrict__ offs2,
                                                const uint_t* __restrict__ srec,
                                                const float* __restrict__ wgt,
                                                const ushort_t* __restrict__ hb,
                                                const float* __restrict__ bias,
                                                float* __restrict__ out) {
    const int n = blockIdx.x * 4 + (threadIdx.x >> 6);
    const int l = threadIdx.x & 63;
    const int c0 = l * 2;              // two channels per lane (same head)
    const int hd = l >> 4;
    const int2 pr = offs2[n];
    const int p0 = pr.x, p1 = pr.y;
    const int deg = p1 - p0;
    float ax = 0.f, ay = 0.f, wsum = 0.f;
    for (int base = 0; base < deg; base += 64) {
        const int m = min(deg - base, 64);
        // one lane-parallel load fetches up to 64 packed records for this node
        const uint_t srcv = srec[p0 + base + ((l < m) ? l : 0)];
        int e = 0;
        for (; e + 8 <= m; e += 8)
            gat8<false>(wgt, hb, srcv, p0, p1, base, e, m, hd, c0, ax, ay, wsum);
        if (e < m)
            gat8<true>(wgt, hb, srcv, p0, p1, base, e, m, hd, c0, ax, ay, wsum);
    }
    const float inv = 1.f / fmaxf(wsum, 1e-10f);
    float2 o;
    o.x = ax * inv + bias[c0];
    o.y = ay * inv + bias[c0 + 1];
    *(float2*)(out + (size_t)n * HO + c0) = o;
}

extern "C" void kernel_launch(void* const* d_in, const int* in_sizes, int n_in,
                              void* d_out, int out_size, void* d_ws, size_t ws_size,
                              hipStream_t stream) {
    const float* x    = (const float*)d_in[0];
    const int*   ei   = (const int*)d_in[1];
    const float* W    = (const float*)d_in[2];
    const float* att  = (const float*)d_in[3];
    const float* bias = (const float*)d_in[4];
    float* out = (float*)d_out;

    char* ws = (char*)d_ws;
    const size_t HB_B  = (size_t)NN * HO * 2;              // 25.6 MB (bf16 h)
    const size_t SR_B  = (size_t)NSLOT * 4;                // 8.0 MB (sorted recs)
    const size_t GR_B  = (size_t)NSLOT * 4;                // 8.0 MB (bucketed recs)
    const size_t WG_B  = (size_t)NSLOT * 16;               // 32.0 MB
    const size_t S_B   = (size_t)NN * HEADS * 4;           // 1.6 MB
    const size_t OF_B  = ((size_t)NN * 8 + 15) & ~15ull;   // 800 KB (int2)
    const size_t GC_B  = ((size_t)NBUCK * 4 + 15) & ~15ull;
    const size_t WT_B  = 32768;                            // 32 KB per W image

    size_t o = 0;
    ushort_t* hb         = (ushort_t*)(ws + o); o += HB_B;
    uint_t*   srec       = (uint_t*)(ws + o); o += SR_B;
    uint_t*   grec       = (uint_t*)(ws + o); o += GR_B;
    float4*   wgt        = (float4*)(ws + o); o += WG_B;
    float*    ssrc       = (float*)(ws + o); o += S_B;
    float*    stgt       = (float*)(ws + o); o += S_B;
    int2*     offs2      = (int2*)(ws + o); o += OF_B;
    int*      gcur       = (int*)(ws + o); o += GC_B;
    ushort_t* gWtHi      = (ushort_t*)(ws + o); o += WT_B;
    ushort_t* gWtLo      = (ushort_t*)(ws + o); o += WT_B;

    (void)hipMemsetAsync(gcur, 0, GC_B, stream);

    fusedPA_k<<<ABLK + 32, 512, 0, stream>>>(ei, gcur, grec,
                                             W, gWtHi, gWtLo);            // 423 blocks
    fusedGS_k<<<NBUCK + GEMMB, 256, 0, stream>>>(grec, gcur, offs2, srec,
                                                 x, gWtHi, gWtLo, att,
                                                 hb, ssrc, stgt);         // 3516 blocks
    wgt_k<<<(NSLOT + 2047) / 2048, 256, 0, stream>>>(srec, gcur,
                                                     ssrc, stgt, wgt);    // 978 blocks
    gather_k<<<NN / 4, 256, 0, stream>>>(offs2, srec, (const float*)wgt,
                                         hb, bias, out);                  // 25000 blocks
}